// Round 20
// baseline (100.524 us; speedup 1.0000x reference)
//
#include <hip/hip_runtime.h>

// SSM: h_t = A h_{t-1} + B x_t ; y_t = C h_t + D x_t
// BATCH=128, T=2048, N=64, f32.
// Round 20 = round 19 with ONE fix: k_gemm1's LDS staging vectorized.
// R19 staged x into LDS via 4 scalar bf16 writes per f32x4 (256 scalar
// ds_write_b16/lane + addr math) -> ~40us kernel. Now: 2x f32x4 load ->
// bf16x8 pack -> one ds_write_b128 (32 iters). Same LA layout bit-for-bit.
//   pipeline: prep -> gemm1 (f=W@x_vec) -> bound1/bsuper/bound2 -> scan2.
// LCH=8, NCH=256, NSUP=16.

#define T_SEQ 2048
#define LCH 8
#define NCH 256

typedef __bf16 bf16x8 __attribute__((ext_vector_type(8)));
typedef float f32x4 __attribute__((ext_vector_type(4)));
typedef float f32x16 __attribute__((ext_vector_type(16)));
typedef unsigned int u32;
typedef unsigned int u32x2 __attribute__((ext_vector_type(2)));

#define MFMA32(a, b, c) __builtin_amdgcn_mfma_f32_32x32x16_bf16(a, b, c, 0, 0, 0)
#define MFMA16(a, b, c) __builtin_amdgcn_mfma_f32_16x16x32_bf16(a, b, c, 0, 0, 0)

// W-table fragment index (64 x 512), B-operand order (round-15/19 validated):
#define WIDX(k, o) (((((long)((o) >> 5) * 32 + ((k) >> 4)) * 64 + \
                      (((k) >> 3) & 1) * 32 + ((o) & 31)) << 3) + ((k) & 7))

typedef __bf16 (*ldsmat)[72];

__device__ __forceinline__ float bcast(float v, int l) {
    return __int_as_float(__builtin_amdgcn_readlane(__float_as_int(v), l));
}
__device__ __forceinline__ u32 pk2f(float a, float b) {
    union { __bf16 h[2]; u32 u; } z;
    z.h[0] = (__bf16)a; z.h[1] = (__bf16)b; return z.u;
}
__device__ __forceinline__ u32 pk2h(__bf16 a, __bf16 b) {
    union { __bf16 h[2]; u32 u; } z;
    z.h[0] = a; z.h[1] = b; return z.u;
}
__device__ __forceinline__ bf16x8 mk8(u32 a, u32 b, u32 c, u32 d) {
    union { u32 u[4]; bf16x8 v; } z;
    z.u[0] = a; z.u[1] = b; z.u[2] = c; z.u[3] = d; return z.v;
}
__device__ __forceinline__ void plswap(u32& a, u32& b) {
    u32x2 r = __builtin_amdgcn_permlane32_swap(a, b, false, false);
    a = r[0]; b = r[1];
}
__device__ __forceinline__ f32x16 z16() {
    f32x16 z;
#pragma unroll
    for (int e = 0; e < 16; ++e) z[e] = 0.f;
    return z;
}
__device__ __forceinline__ void split8(f32x4 a, f32x4 b, bf16x8& hi, bf16x8& lo) {
#pragma unroll
    for (int i = 0; i < 4; ++i) {
        float v = a[i]; __bf16 h = (__bf16)v; hi[i] = h; lo[i] = (__bf16)(v - (float)h);
        v = b[i]; h = (__bf16)v; hi[4 + i] = h; lo[4 + i] = (__bf16)(v - (float)h);
    }
}

// C/D tile (f32x16) -> B-operand frags (kc=0,1) hi+lo, via permlane swaps.
__device__ __forceinline__ void feedback(const f32x16& ac,
        bf16x8& gh0, bf16x8& gl0, bf16x8& gh1, bf16x8& gl1) {
    __bf16 hb[16]; float lo[16];
#pragma unroll
    for (int e = 0; e < 16; ++e) { hb[e] = (__bf16)ac[e]; lo[e] = ac[e] - (float)hb[e]; }
    u32 a0 = pk2h(hb[0], hb[1]),  a1 = pk2h(hb[2], hb[3]);
    u32 b0 = pk2h(hb[4], hb[5]),  b1 = pk2h(hb[6], hb[7]);
    u32 c0 = pk2h(hb[8], hb[9]),  c1 = pk2h(hb[10], hb[11]);
    u32 d0 = pk2h(hb[12], hb[13]), d1 = pk2h(hb[14], hb[15]);
    plswap(a0, b0); plswap(a1, b1);
    gh0 = mk8(a0, a1, b0, b1);
    plswap(c0, d0); plswap(c1, d1);
    gh1 = mk8(c0, c1, d0, d1);
    u32 e0 = pk2f(lo[0], lo[1]),  e1 = pk2f(lo[2], lo[3]);
    u32 f0 = pk2f(lo[4], lo[5]),  f1 = pk2f(lo[6], lo[7]);
    u32 g0 = pk2f(lo[8], lo[9]),  g1 = pk2f(lo[10], lo[11]);
    u32 h0 = pk2f(lo[12], lo[13]), h1 = pk2f(lo[14], lo[15]);
    plswap(e0, f0); plswap(e1, f1);
    gl0 = mk8(e0, e1, f0, f1);
    plswap(g0, h0); plswap(g1, h1);
    gl1 = mk8(g0, g1, h0, h1);
}

// ---------------- prep helpers (16x16 split-MFMA on 64x64 LDS mats) --------
__device__ __forceinline__ void mm_core(int w, int fr, int fq,
        const __bf16 (*Xh)[72], const __bf16 (*Xl)[72],
        const __bf16 (*Yh)[72], const __bf16 (*Yl)[72], f32x4* accs) {
#pragma unroll
    for (int mt = 0; mt < 4; ++mt) {
        f32x4 acc = {0.f, 0.f, 0.f, 0.f};
#pragma unroll
        for (int kk = 0; kk < 2; ++kk) {
            bf16x8 xh = *(const bf16x8*)&Xh[mt * 16 + fr][fq * 8 + kk * 32];
            bf16x8 xl = *(const bf16x8*)&Xl[mt * 16 + fr][fq * 8 + kk * 32];
            bf16x8 yh = *(const bf16x8*)&Yh[w * 16 + fr][fq * 8 + kk * 32];
            bf16x8 yl = *(const bf16x8*)&Yl[w * 16 + fr][fq * 8 + kk * 32];
            acc = MFMA16(xh, yh, acc);
            acc = MFMA16(xh, yl, acc);
            acc = MFMA16(xl, yh, acc);
        }
        accs[mt] = acc;
    }
}
__device__ __forceinline__ void acc_to_lds(int w, int fr, int fq,
        const f32x4* accs, __bf16 (*Dh)[72], __bf16 (*Dl)[72]) {
#pragma unroll
    for (int mt = 0; mt < 4; ++mt)
#pragma unroll
        for (int r = 0; r < 4; ++r) {
            float v = accs[mt][r]; __bf16 h = (__bf16)v;
            Dh[mt * 16 + fq * 4 + r][w * 16 + fr] = h;
            Dl[mt * 16 + fq * 4 + r][w * 16 + fr] = (__bf16)(v - (float)h);
        }
}
__device__ __forceinline__ void stage_split(const float* __restrict__ M, int tid,
        __bf16 (*Mh)[72], __bf16 (*Ml)[72]) {
    for (int i = tid; i < 4096; i += 256) {
        float v = M[i]; __bf16 h = (__bf16)v;
        Mh[i >> 6][i & 63] = h; Ml[i >> 6][i & 63] = (__bf16)(v - (float)h);
    }
}
__device__ __forceinline__ void stage_split_T(const float* __restrict__ M, int tid,
        __bf16 (*Mh)[72], __bf16 (*Ml)[72]) {
    for (int i = tid; i < 4096; i += 256) {
        int k = i >> 6, d = i & 63;
        float v = M[i]; __bf16 h = (__bf16)v;
        Mh[d][k] = h; Ml[d][k] = (__bf16)(v - (float)h);
    }
}

// ---------------- k_prep: Wfrag (A^j B), P8/P128, operand splits -----------
// bid 0..6 -> j=bid+1: W_{7-j} = A^j @ B.  bid 7: squarings -> P8, P128.
// bid 8: A/B/C/D splits + W_7 = B.
__global__ __launch_bounds__(256) void k_prep(const float* __restrict__ A,
        const float* __restrict__ B, const float* __restrict__ C,
        const float* __restrict__ D, float* __restrict__ P8,
        float* __restrict__ P128,
        __bf16* __restrict__ A_hi, __bf16* __restrict__ A_lo,
        __bf16* __restrict__ B_bf, __bf16* __restrict__ C_bf,
        __bf16* __restrict__ D_bf, __bf16* __restrict__ Wfrag) {
    int tid = threadIdx.x;
    int bid = blockIdx.x;
    if (bid == 8) {
        for (int i = tid; i < 4096; i += 256) {
            float a = A[i]; __bf16 h = (__bf16)a;
            A_hi[i] = h; A_lo[i] = (__bf16)(a - (float)h);
            B_bf[i] = (__bf16)B[i];
            C_bf[i] = (__bf16)C[i];
            D_bf[i] = (__bf16)D[i];
            int o = i >> 6, d = i & 63;
            Wfrag[WIDX(7 * 64 + d, o)] = (__bf16)B[i];   // W_7 = B
        }
        return;
    }
    __shared__ __align__(16) __bf16 U1h[64][72], U1l[64][72];
    __shared__ __align__(16) __bf16 U2h[64][72], U2l[64][72];
    __shared__ __align__(16) __bf16 U3h[64][72], U3l[64][72];
    int w = tid >> 6, lane = tid & 63, fr = lane & 15, fq = lane >> 4;
    f32x4 accs[4];

    if (bid == 7) {      // squarings: A^2..A^128; emit A^8, A^128
        stage_split(A, tid, U1h, U1l);
        __syncthreads();
        ldsmat curh = U1h, curl = U1l, oth = U2h, otl = U2l;
        for (int sq = 0; sq < 7; ++sq) {
            mm_core(w, fr, fq, curh, curl, curh, curl, accs);
            __syncthreads();
            acc_to_lds(w, fr, fq, accs, oth, otl);
            __syncthreads();
            { ldsmat t = curh; curh = oth; oth = t;
              t = curl; curl = otl; otl = t; }
            if (sq == 2)
                for (int i = tid; i < 4096; i += 256)
                    P8[i] = (float)curh[i >> 6][i & 63] + (float)curl[i >> 6][i & 63];
        }
        for (int i = tid; i < 4096; i += 256)
            P128[i] = (float)curh[i >> 6][i & 63] + (float)curl[i >> 6][i & 63];
        return;
    }
    // bid 0..6 -> j = bid+1: chain A^j, then W = A^j @ B
    int j = bid + 1;
    stage_split(A, tid, U1h, U1l);
    stage_split(A, tid, U3h, U3l);
    __syncthreads();
    ldsmat curh = U1h, curl = U1l, oth = U2h, otl = U2l;
    for (int s = 1; s < j; ++s) {               // cur = cur @ A
        mm_core(w, fr, fq, curh, curl, U3h, U3l, accs);
        __syncthreads();
        acc_to_lds(w, fr, fq, accs, oth, otl);
        __syncthreads();
        { ldsmat t = curh; curh = oth; oth = t;
          t = curl; curl = otl; otl = t; }
    }
    stage_split_T(B, tid, oth, otl);            // oth = B^T (row-read => B)
    __syncthreads();
    mm_core(w, fr, fq, curh, curl, oth, otl, accs);   // A^j @ B
#pragma unroll
    for (int mt = 0; mt < 4; ++mt)
#pragma unroll
        for (int r = 0; r < 4; ++r) {
            int row = mt * 16 + fq * 4 + r, col = w * 16 + fr;
            Wfrag[WIDX((7 - j) * 64 + col, row)] = (__bf16)accs[mt][r];
        }
}

// ---------------- k_gemm1: f_c = W @ x_vec (staging VECTORIZED) ------------
__global__ __launch_bounds__(64) void k_gemm1(const float* __restrict__ x,
        const __bf16* __restrict__ Wfrag, float* __restrict__ fbuf) {
    __shared__ __bf16 LA[32][64][8];
    int lane = threadIdx.x;
    int c = blockIdx.x >> 2, bg = blockIdx.x & 3;
    // stage: 32 iters of (2x f32x4 load -> bf16x8 pack -> one ds_write_b128)
#pragma unroll 4
    for (int it = 0; it < 32; ++it) {
        int q = lane + 64 * it;              // 0..2047
        int dq = (q & 7) * 8;                // 0,8,..,56
        int b  = (q >> 3) & 31;
        int t2 = q >> 8;                     // 0..7
        const float* p = x + ((long)(bg * 32 + b) * T_SEQ + c * 8 + t2) * 64 + dq;
        f32x4 v0 = *(const f32x4*)(p);
        f32x4 v1 = *(const f32x4*)(p + 4);
        bf16x8 pk = mk8(pk2f(v0[0], v0[1]), pk2f(v0[2], v0[3]),
                        pk2f(v1[0], v1[1]), pk2f(v1[2], v1[3]));
        int k = t2 * 64 + dq;                // multiple of 8
        *(bf16x8*)&LA[k >> 4][((k >> 3) & 1) * 32 + b][0] = pk;
    }
    __syncthreads();
    int bcol = lane & 31, hl = lane >> 5;
    f32x16 a0 = z16(), a1 = z16();
    for (int kt = 0; kt < 32; ++kt) {
        bf16x8 a = *(const bf16x8*)&LA[kt][lane][0];
        a0 = MFMA32(a, *(const bf16x8*)(Wfrag + (((long)kt * 64 + lane) << 3)), a0);
        a1 = MFMA32(a, *(const bf16x8*)(Wfrag + (((long)(32 + kt) * 64 + lane) << 3)), a1);
    }
    float* fp = fbuf + ((long)c * 128 + bg * 32) * 64;
#pragma unroll
    for (int r = 0; r < 16; ++r) {
        int row = (r & 3) + 8 * (r >> 2) + 4 * hl;
        fp[(long)row * 64 + bcol] = a0[r];
        fp[(long)row * 64 + 32 + bcol] = a1[r];
    }
}

// ---------------- boundary scans (round-18/19 proven) ----------------------
__global__ __launch_bounds__(256) void k_bound1(const float* __restrict__ P,
        const float* __restrict__ fbuf, float* __restrict__ Fsup, int nper) {
    int wid = blockIdx.x * 4 + (threadIdx.x >> 6);
    int lane = threadIdx.x & 63;
    int s = wid >> 7, batch = wid & 127;
    float Pr[64];
    const f32x4* P4 = (const f32x4*)(P + lane * 64);
#pragma unroll
    for (int qq = 0; qq < 16; ++qq) {
        f32x4 v = P4[qq];
        Pr[qq*4] = v[0]; Pr[qq*4+1] = v[1]; Pr[qq*4+2] = v[2]; Pr[qq*4+3] = v[3];
    }
    float S = 0.f;
    for (int i = 0; i < nper; ++i) {
        int c = s * nper + i;
        float fv = fbuf[((long)c * 128 + batch) * 64 + lane];
        float a0 = fv, a1 = 0.f;
#pragma unroll
        for (int m = 0; m < 64; m += 2) {
            a0 = fmaf(Pr[m],     bcast(S, m),     a0);
            a1 = fmaf(Pr[m + 1], bcast(S, m + 1), a1);
        }
        S = a0 + a1;
    }
    Fsup[((long)s * 128 + batch) * 64 + lane] = S;
}

__global__ __launch_bounds__(256) void k_bsuper(const float* __restrict__ P,
        float* __restrict__ Fsup, int nsup) {
    int batch = blockIdx.x * 4 + (threadIdx.x >> 6);
    int lane = threadIdx.x & 63;
    float Pr[64];
    const f32x4* P4 = (const f32x4*)(P + lane * 64);
#pragma unroll
    for (int qq = 0; qq < 16; ++qq) {
        f32x4 v = P4[qq];
        Pr[qq*4] = v[0]; Pr[qq*4+1] = v[1]; Pr[qq*4+2] = v[2]; Pr[qq*4+3] = v[3];
    }
    float E = 0.f;
    for (int s = 0; s < nsup; ++s) {
        long idx = ((long)s * 128 + batch) * 64 + lane;
        float tmp = Fsup[idx];
        Fsup[idx] = E;
        float a0 = tmp, a1 = 0.f;
#pragma unroll
        for (int m = 0; m < 64; m += 2) {
            a0 = fmaf(Pr[m],     bcast(E, m),     a0);
            a1 = fmaf(Pr[m + 1], bcast(E, m + 1), a1);
        }
        E = a0 + a1;
    }
}

__global__ __launch_bounds__(256) void k_bound2(const float* __restrict__ P,
        const float* __restrict__ Fsup, float* __restrict__ fbuf, int nper) {
    int wid = blockIdx.x * 4 + (threadIdx.x >> 6);
    int lane = threadIdx.x & 63;
    int s = wid >> 7, batch = wid & 127;
    float Pr[64];
    const f32x4* P4 = (const f32x4*)(P + lane * 64);
#pragma unroll
    for (int qq = 0; qq < 16; ++qq) {
        f32x4 v = P4[qq];
        Pr[qq*4] = v[0]; Pr[qq*4+1] = v[1]; Pr[qq*4+2] = v[2]; Pr[qq*4+3] = v[3];
    }
    float S = Fsup[((long)s * 128 + batch) * 64 + lane];
    for (int i = 0; i < nper; ++i) {
        int c = s * nper + i;
        long idx = ((long)c * 128 + batch) * 64 + lane;
        float tmp = fbuf[idx];
        fbuf[idx] = S;                 // entry state of chunk c
        float a0 = tmp, a1 = 0.f;
#pragma unroll
        for (int m = 0; m < 64; m += 2) {
            a0 = fmaf(Pr[m],     bcast(S, m),     a0);
            a1 = fmaf(Pr[m + 1], bcast(S, m + 1), a1);
        }
        S = a0 + a1;
    }
}

// ---------------- k_scan2 (round-18/19 proven recurrence) ------------------
__global__ __launch_bounds__(64, 1) void k_scan2(const float* __restrict__ x,
        const float* __restrict__ Sbuf,
        const __bf16* __restrict__ A_hi, const __bf16* __restrict__ A_lo,
        const __bf16* __restrict__ B_bf, const __bf16* __restrict__ C_bf,
        const __bf16* __restrict__ D_bf, float* __restrict__ y) {
    int lane = threadIdx.x & 63;
    int bcol = lane & 31;
    int hl = lane >> 5;
    int wid = blockIdx.x;
    int g = wid >> 8;            // batch group 0..3
    int c = wid & 255;           // chunk 0..255
    int t0 = c * LCH;
    long brow = (long)(g * 32 + bcol);

    bf16x8 Afh[2][2][2], Afl[2][2][2], Bf[2][2][2], Cf[2][2][2], Df[2][2][2];
#pragma unroll
    for (int i = 0; i < 2; ++i)
#pragma unroll
        for (int j = 0; j < 2; ++j)
#pragma unroll
            for (int kc = 0; kc < 2; ++kc) {
                int off = (32 * i + bcol) * 64 + 32 * j + 16 * kc + 8 * hl;
                Afh[i][j][kc] = *(const bf16x8*)(A_hi + off);
                Afl[i][j][kc] = *(const bf16x8*)(A_lo + off);
                Bf[i][j][kc]  = *(const bf16x8*)(B_bf + off);
                Cf[i][j][kc]  = *(const bf16x8*)(C_bf + off);
                Df[i][j][kc]  = *(const bf16x8*)(D_bf + off);
            }

    bf16x8 Gh[2][2], Gl[2][2];
    {
        const float* Sp = Sbuf + ((long)c * 128 + brow) * 64;
#pragma unroll
        for (int jr = 0; jr < 2; ++jr)
#pragma unroll
            for (int kc = 0; kc < 2; ++kc) {
                int n0 = 32 * jr + 16 * kc + 8 * hl;
                f32x4 s0 = *(const f32x4*)(Sp + n0);
                f32x4 s1 = *(const f32x4*)(Sp + n0 + 4);
                split8(s0, s1, Gh[jr][kc], Gl[jr][kc]);
            }
    }

    const float* xb = x + (brow * T_SEQ + t0) * 64 + 8 * hl;
    f32x4 XF[8]; bf16x8 XB[2][2];
#define LOADX(dt) { const float* p = xb + (long)(dt) * 64;                     \
    XF[0] = *(const f32x4*)(p);      XF[1] = *(const f32x4*)(p + 4);           \
    XF[2] = *(const f32x4*)(p + 16); XF[3] = *(const f32x4*)(p + 20);          \
    XF[4] = *(const f32x4*)(p + 32); XF[5] = *(const f32x4*)(p + 36);          \
    XF[6] = *(const f32x4*)(p + 48); XF[7] = *(const f32x4*)(p + 52); }
#define CVTX() {                                                               \
    XB[0][0] = mk8(pk2f(XF[0][0], XF[0][1]), pk2f(XF[0][2], XF[0][3]),         \
                   pk2f(XF[1][0], XF[1][1]), pk2f(XF[1][2], XF[1][3]));        \
    XB[0][1] = mk8(pk2f(XF[2][0], XF[2][1]), pk2f(XF[2][2], XF[2][3]),         \
                   pk2f(XF[3][0], XF[3][1]), pk2f(XF[3][2], XF[3][3]));        \
    XB[1][0] = mk8(pk2f(XF[4][0], XF[4][1]), pk2f(XF[4][2], XF[4][3]),         \
                   pk2f(XF[5][0], XF[5][1]), pk2f(XF[5][2], XF[5][3]));        \
    XB[1][1] = mk8(pk2f(XF[6][0], XF[6][1]), pk2f(XF[6][2], XF[6][3]),         \
                   pk2f(XF[7][0], XF[7][1]), pk2f(XF[7][2], XF[7][3])); }

    LOADX(0); CVTX(); LOADX(1);

    float* yb = y + brow * T_SEQ * 64;
    f32x16 ac0, ac1;
#pragma unroll
    for (int st = 0; st < LCH; ++st) {
        ac0 = z16(); ac1 = z16();
#pragma unroll
        for (int j = 0; j < 2; ++j)
#pragma unroll
            for (int kc = 0; kc < 2; ++kc) {
                ac0 = MFMA32(Bf[0][j][kc], XB[j][kc], ac0);
                ac1 = MFMA32(Bf[1][j][kc], XB[j][kc], ac1);
            }
#pragma unroll
        for (int jr = 0; jr < 2; ++jr)
#pragma unroll
            for (int kc = 0; kc < 2; ++kc) {
                ac0 = MFMA32(Afh[0][jr][kc], Gh[jr][kc], ac0);
                ac0 = MFMA32(Afh[0][jr][kc], Gl[jr][kc], ac0);
                ac0 = MFMA32(Afl[0][jr][kc], Gh[jr][kc], ac0);
                ac1 = MFMA32(Afh[1][jr][kc], Gh[jr][kc], ac1);
                ac1 = MFMA32(Afh[1][jr][kc], Gl[jr][kc], ac1);
                ac1 = MFMA32(Afl[1][jr][kc], Gh[jr][kc], ac1);
            }
        feedback(ac0, Gh[0][0], Gl[0][0], Gh[0][1], Gl[0][1]);
        feedback(ac1, Gh[1][0], Gl[1][0], Gh[1][1], Gl[1][1]);
        {
            float* yp = yb + (long)(t0 + st) * 64;
#pragma unroll
            for (int i = 0; i < 2; ++i) {
                f32x16 ya = z16();
#pragma unroll
                for (int jr = 0; jr < 2; ++jr)
#pragma unroll
                    for (int kc = 0; kc < 2; ++kc) {
                        ya = MFMA32(Cf[i][jr][kc], Gh[jr][kc], ya);
                        ya = MFMA32(Cf[i][jr][kc], Gl[jr][kc], ya);
                        ya = MFMA32(Df[i][jr][kc], XB[jr][kc], ya);
                    }
#pragma unroll
                for (int m = 0; m < 4; ++m) {
                    f32x4 v;
                    v[0] = ya[4 * m]; v[1] = ya[4 * m + 1];
                    v[2] = ya[4 * m + 2]; v[3] = ya[4 * m + 3];
                    *(f32x4*)(yp + 32 * i + 8 * m + 4 * hl) = v;
                }
            }
        }
        // rotate x: XB <- XF(t+1); prefetch XF(t+2) (clamped)
        CVTX();
        int nt = st + 2;
        if (t0 + nt > T_SEQ - 1) nt = T_SEQ - 1 - t0;
        LOADX(nt);
    }
#undef LOADX
#undef CVTX
}

extern "C" void kernel_launch(void* const* d_in, const int* in_sizes, int n_in,
                              void* d_out, int out_size, void* d_ws, size_t ws_size,
                              hipStream_t stream) {
    const float* x = (const float*)d_in[0];
    const float* A = (const float*)d_in[1];
    const float* B = (const float*)d_in[2];
    const float* C = (const float*)d_in[3];
    const float* D = (const float*)d_in[4];
    float* y = (float*)d_out;
    char* ws = (char*)d_ws;

    float*  fbuf  = (float*)(ws);                 // 256*128*64*4 = 8,388,608
    float*  Fsup  = (float*)(ws + 8388608);       // 16*128*64*4 = 524,288
    float*  P8    = (float*)(ws + 8912896);       // 16,384
    float*  P128  = (float*)(ws + 8929280);       // 16,384
    __bf16* A_hi  = (__bf16*)(ws + 8945664);      // 8,192 each
    __bf16* A_lo  = (__bf16*)(ws + 8953856);
    __bf16* B_bf  = (__bf16*)(ws + 8962048);
    __bf16* C_bf  = (__bf16*)(ws + 8970240);
    __bf16* D_bf  = (__bf16*)(ws + 8978432);
    __bf16* Wfrag = (__bf16*)(ws + 8986624);      // 64*512*2 = 65,536
    // total 9,052,160 B

    k_prep<<<9, 256, 0, stream>>>(A, B, C, D, P8, P128,
                                  A_hi, A_lo, B_bf, C_bf, D_bf, Wfrag);
    k_gemm1<<<1024, 64, 0, stream>>>(x, Wfrag, fbuf);
    k_bound1<<<512, 256, 0, stream>>>(P8, fbuf, Fsup, 16);
    k_bsuper<<<32, 256, 0, stream>>>(P128, Fsup, 16);
    k_bound2<<<512, 256, 0, stream>>>(P8, Fsup, fbuf, 16);
    k_scan2<<<1024, 64, 0, stream>>>(x, fbuf, A_hi, A_lo, B_bf, C_bf, D_bf, y);
}

// Round 21
// 98.077 us; speedup vs baseline: 1.0249x; 1.0249x over previous
//
#include <hip/hip_runtime.h>

// SSM: h_t = A h_{t-1} + B x_t ; y_t = C h_t + D x_t
// BATCH=128, T=2048, N=64, f32. Transposed state (A symmetric):
//   G = h^T (64 x 32batch): G_t = A*G_{t-1} + B*x_t^T
// Round 21 = round 18 (97.4us, passing) + ILP RESTRUCTURE of scan_core:
// each acc's 16 dependent scan MFMAs -> 4 independent chains of 4
// (B.x | Afh.Gh | Afh.Gl | Afl.Gh), combined by 3 f32x16 adds; y-phase
// likewise 3 chains of 4 per tile. At 1 wave/SIMD the step was
// dependent-MFMA-latency bound (~4.9us/step for 52 MFMAs); chains give
// 8-way ILP. Same math (f32-add reassociation only).
// LCH=8, NCH=256, NSUP=16.

#define T_SEQ 2048
#define LCH 8
#define NCH 256
#define NSUP 16

typedef __bf16 bf16x8 __attribute__((ext_vector_type(8)));
typedef float f32x4 __attribute__((ext_vector_type(4)));
typedef float f32x16 __attribute__((ext_vector_type(16)));
typedef unsigned int u32;
typedef unsigned int u32x2 __attribute__((ext_vector_type(2)));

#define MFMA32(a, b, c) __builtin_amdgcn_mfma_f32_32x32x16_bf16(a, b, c, 0, 0, 0)
#define MFMA16(a, b, c) __builtin_amdgcn_mfma_f32_16x16x32_bf16(a, b, c, 0, 0, 0)

__device__ __forceinline__ float bcast(float v, int l) {
    return __int_as_float(__builtin_amdgcn_readlane(__float_as_int(v), l));
}
__device__ __forceinline__ u32 pk2f(float a, float b) {
    union { __bf16 h[2]; u32 u; } z;
    z.h[0] = (__bf16)a; z.h[1] = (__bf16)b; return z.u;
}
__device__ __forceinline__ u32 pk2h(__bf16 a, __bf16 b) {
    union { __bf16 h[2]; u32 u; } z;
    z.h[0] = a; z.h[1] = b; return z.u;
}
__device__ __forceinline__ bf16x8 mk8(u32 a, u32 b, u32 c, u32 d) {
    union { u32 u[4]; bf16x8 v; } z;
    z.u[0] = a; z.u[1] = b; z.u[2] = c; z.u[3] = d; return z.v;
}
__device__ __forceinline__ void plswap(u32& a, u32& b) {
    u32x2 r = __builtin_amdgcn_permlane32_swap(a, b, false, false);
    a = r[0]; b = r[1];
}
__device__ __forceinline__ f32x16 z16() {
    f32x16 z;
#pragma unroll
    for (int e = 0; e < 16; ++e) z[e] = 0.f;
    return z;
}
__device__ __forceinline__ void split8(f32x4 a, f32x4 b, bf16x8& hi, bf16x8& lo) {
#pragma unroll
    for (int i = 0; i < 4; ++i) {
        float v = a[i]; __bf16 h = (__bf16)v; hi[i] = h; lo[i] = (__bf16)(v - (float)h);
        v = b[i]; h = (__bf16)v; hi[4 + i] = h; lo[4 + i] = (__bf16)(v - (float)h);
    }
}

// C/D tile (f32x16) -> B-operand frags (kc=0,1) hi+lo, via permlane swaps.
__device__ __forceinline__ void feedback(const f32x16& ac,
        bf16x8& gh0, bf16x8& gl0, bf16x8& gh1, bf16x8& gl1) {
    __bf16 hb[16]; float lo[16];
#pragma unroll
    for (int e = 0; e < 16; ++e) { hb[e] = (__bf16)ac[e]; lo[e] = ac[e] - (float)hb[e]; }
    u32 a0 = pk2h(hb[0], hb[1]),  a1 = pk2h(hb[2], hb[3]);
    u32 b0 = pk2h(hb[4], hb[5]),  b1 = pk2h(hb[6], hb[7]);
    u32 c0 = pk2h(hb[8], hb[9]),  c1 = pk2h(hb[10], hb[11]);
    u32 d0 = pk2h(hb[12], hb[13]), d1 = pk2h(hb[14], hb[15]);
    plswap(a0, b0); plswap(a1, b1);
    gh0 = mk8(a0, a1, b0, b1);
    plswap(c0, d0); plswap(c1, d1);
    gh1 = mk8(c0, c1, d0, d1);
    u32 e0 = pk2f(lo[0], lo[1]),  e1 = pk2f(lo[2], lo[3]);
    u32 f0 = pk2f(lo[4], lo[5]),  f1 = pk2f(lo[6], lo[7]);
    u32 g0 = pk2f(lo[8], lo[9]),  g1 = pk2f(lo[10], lo[11]);
    u32 h0 = pk2f(lo[12], lo[13]), h1 = pk2f(lo[14], lo[15]);
    plswap(e0, f0); plswap(e1, f1);
    gl0 = mk8(e0, e1, f0, f1);
    plswap(g0, h0); plswap(g1, h1);
    gl1 = mk8(g0, g1, h0, h1);
}

// ---------------- k_prep (16x16 split-MFMA squarings; proven) --------------
__device__ __forceinline__ void mmstep(int w, int fr, int fq,
        const __bf16 (*Xh)[72], const __bf16 (*Xl)[72],
        const __bf16 (*Yh)[72], const __bf16 (*Yl)[72],
        __bf16 (*Dh)[72], __bf16 (*Dl)[72]) {
    f32x4 accs[4];
#pragma unroll
    for (int mt = 0; mt < 4; ++mt) {
        f32x4 acc = {0.f, 0.f, 0.f, 0.f};
#pragma unroll
        for (int kk = 0; kk < 2; ++kk) {
            bf16x8 xh = *(const bf16x8*)&Xh[mt * 16 + fr][fq * 8 + kk * 32];
            bf16x8 xl = *(const bf16x8*)&Xl[mt * 16 + fr][fq * 8 + kk * 32];
            bf16x8 yh = *(const bf16x8*)&Yh[w * 16 + fr][fq * 8 + kk * 32];
            bf16x8 yl = *(const bf16x8*)&Yl[w * 16 + fr][fq * 8 + kk * 32];
            acc = MFMA16(xh, yh, acc);
            acc = MFMA16(xh, yl, acc);
            acc = MFMA16(xl, yh, acc);
        }
        accs[mt] = acc;
    }
    __syncthreads();
#pragma unroll
    for (int mt = 0; mt < 4; ++mt)
#pragma unroll
        for (int r = 0; r < 4; ++r) {
            float v = accs[mt][r]; __bf16 h = (__bf16)v;
            Dh[mt * 16 + fq * 4 + r][w * 16 + fr] = h;
            Dl[mt * 16 + fq * 4 + r][w * 16 + fr] = (__bf16)(v - (float)h);
        }
    __syncthreads();
}

__global__ __launch_bounds__(256) void k_prep(const float* __restrict__ A,
        const float* __restrict__ B, const float* __restrict__ C,
        const float* __restrict__ D, float* __restrict__ P8,
        float* __restrict__ P128,
        __bf16* __restrict__ A_hi, __bf16* __restrict__ A_lo,
        __bf16* __restrict__ B_bf, __bf16* __restrict__ C_bf,
        __bf16* __restrict__ D_bf) {
    if (blockIdx.x == 1) {
        for (int i = threadIdx.x; i < 4096; i += 256) {
            float a = A[i]; __bf16 h = (__bf16)a;
            A_hi[i] = h; A_lo[i] = (__bf16)(a - (float)h);
            B_bf[i] = (__bf16)B[i];
            C_bf[i] = (__bf16)C[i];
            D_bf[i] = (__bf16)D[i];
        }
        return;
    }
    __shared__ __align__(16) __bf16 X1h[64][72], X1l[64][72];
    __shared__ __align__(16) __bf16 X2h[64][72], X2l[64][72];
    int w = threadIdx.x >> 6, lane = threadIdx.x & 63;
    int fr = lane & 15, fq = lane >> 4;
    for (int i = threadIdx.x; i < 4096; i += 256) {
        int r = i >> 6, cc = i & 63;
        float a = A[i]; __bf16 h = (__bf16)a;
        X1h[r][cc] = h; X1l[r][cc] = (__bf16)(a - (float)h);
    }
    __syncthreads();
    __bf16 (*curh)[72] = X1h, (*curl)[72] = X1l;
    __bf16 (*oth)[72] = X2h, (*otl)[72] = X2l;
    for (int sq = 0; sq < 7; ++sq) {   // A^2,4,8,16,32,64,128
        mmstep(w, fr, fq, curh, curl, curh, curl, oth, otl);
        { __bf16 (*t1)[72] = curh; curh = oth; oth = t1;
          __bf16 (*t2)[72] = curl; curl = otl; otl = t2; }
        if (sq == 2) {                 // A^8
            for (int i = threadIdx.x; i < 4096; i += 256)
                P8[i] = (float)curh[i >> 6][i & 63] + (float)curl[i >> 6][i & 63];
        }
    }
    for (int i = threadIdx.x; i < 4096; i += 256)
        P128[i] = (float)curh[i >> 6][i & 63] + (float)curl[i >> 6][i & 63];
}

// ---------------- scan core (32x32 tiles, LDS-free, ILP chains) ------------
// Layouts (mfma_f32_32x32x16_bf16):
//   A-op: lane l -> M[row=l&31][k=8*(l>>5)+e (+16kc)]
//   B-op: lane l -> M[k=8*(l>>5)+e (+16kc)][col=l&31]
//   C/D : lane l -> D[row=(r&3)+8*(r>>2)+4*(l>>5)][col=l&31]
template<bool DOY>
__device__ __forceinline__ void scan_core(const float* __restrict__ x,
        const float* __restrict__ Sbuf,
        const __bf16* __restrict__ A_hi, const __bf16* __restrict__ A_lo,
        const __bf16* __restrict__ B_bf, const __bf16* __restrict__ C_bf,
        const __bf16* __restrict__ D_bf,
        float* __restrict__ fbuf, float* __restrict__ y) {
    int lane = threadIdx.x & 63;
    int bcol = lane & 31;
    int hl = lane >> 5;
    int wid = blockIdx.x;
    int g = wid >> 8;            // batch group 0..3
    int c = wid & 255;           // chunk 0..255
    int t0 = c * LCH;
    long brow = (long)(g * 32 + bcol);

    bf16x8 Afh[2][2][2], Afl[2][2][2], Bf[2][2][2], Cf[2][2][2], Df[2][2][2];
#pragma unroll
    for (int i = 0; i < 2; ++i)
#pragma unroll
        for (int j = 0; j < 2; ++j)
#pragma unroll
            for (int kc = 0; kc < 2; ++kc) {
                int off = (32 * i + bcol) * 64 + 32 * j + 16 * kc + 8 * hl;
                Afh[i][j][kc] = *(const bf16x8*)(A_hi + off);
                Afl[i][j][kc] = *(const bf16x8*)(A_lo + off);
                Bf[i][j][kc]  = *(const bf16x8*)(B_bf + off);
                if (DOY) {
                    Cf[i][j][kc] = *(const bf16x8*)(C_bf + off);
                    Df[i][j][kc] = *(const bf16x8*)(D_bf + off);
                }
            }

    bf16x8 Gh[2][2], Gl[2][2];
    if (DOY) {
        const float* Sp = Sbuf + ((long)c * 128 + brow) * 64;
#pragma unroll
        for (int jr = 0; jr < 2; ++jr)
#pragma unroll
            for (int kc = 0; kc < 2; ++kc) {
                int n0 = 32 * jr + 16 * kc + 8 * hl;
                f32x4 s0 = *(const f32x4*)(Sp + n0);
                f32x4 s1 = *(const f32x4*)(Sp + n0 + 4);
                split8(s0, s1, Gh[jr][kc], Gl[jr][kc]);
            }
    } else {
#pragma unroll
        for (int jr = 0; jr < 2; ++jr)
#pragma unroll
            for (int kc = 0; kc < 2; ++kc) {
                Gh[jr][kc] = (bf16x8)(__bf16)0.f;
                Gl[jr][kc] = (bf16x8)(__bf16)0.f;
            }
    }

    const float* xb = x + (brow * T_SEQ + t0) * 64 + 8 * hl;
    f32x4 XF[8]; bf16x8 XB[2][2];
#define LOADX(dt) { const float* p = xb + (long)(dt) * 64;                     \
    XF[0] = *(const f32x4*)(p);      XF[1] = *(const f32x4*)(p + 4);           \
    XF[2] = *(const f32x4*)(p + 16); XF[3] = *(const f32x4*)(p + 20);          \
    XF[4] = *(const f32x4*)(p + 32); XF[5] = *(const f32x4*)(p + 36);          \
    XF[6] = *(const f32x4*)(p + 48); XF[7] = *(const f32x4*)(p + 52); }
#define CVTX() {                                                               \
    XB[0][0] = mk8(pk2f(XF[0][0], XF[0][1]), pk2f(XF[0][2], XF[0][3]),         \
                   pk2f(XF[1][0], XF[1][1]), pk2f(XF[1][2], XF[1][3]));        \
    XB[0][1] = mk8(pk2f(XF[2][0], XF[2][1]), pk2f(XF[2][2], XF[2][3]),         \
                   pk2f(XF[3][0], XF[3][1]), pk2f(XF[3][2], XF[3][3]));        \
    XB[1][0] = mk8(pk2f(XF[4][0], XF[4][1]), pk2f(XF[4][2], XF[4][3]),         \
                   pk2f(XF[5][0], XF[5][1]), pk2f(XF[5][2], XF[5][3]));        \
    XB[1][1] = mk8(pk2f(XF[6][0], XF[6][1]), pk2f(XF[6][2], XF[6][3]),         \
                   pk2f(XF[7][0], XF[7][1]), pk2f(XF[7][2], XF[7][3])); }

    LOADX(0); CVTX(); LOADX(1);

    float* yb = DOY ? (y + brow * T_SEQ * 64) : nullptr;
    f32x16 ac0, ac1;
#pragma unroll
    for (int st = 0; st < LCH; ++st) {
        // 8 independent chains of 4 MFMAs (B.x | Afh.Gh | Afh.Gl | Afl.Gh) x2
        f32x16 cA0 = z16(), cB0 = z16(), cC0 = z16(), cD0 = z16();
        f32x16 cA1 = z16(), cB1 = z16(), cC1 = z16(), cD1 = z16();
#pragma unroll
        for (int j = 0; j < 2; ++j)
#pragma unroll
            for (int kc = 0; kc < 2; ++kc) {
                cA0 = MFMA32(Bf[0][j][kc], XB[j][kc], cA0);
                cA1 = MFMA32(Bf[1][j][kc], XB[j][kc], cA1);
                cB0 = MFMA32(Afh[0][j][kc], Gh[j][kc], cB0);
                cB1 = MFMA32(Afh[1][j][kc], Gh[j][kc], cB1);
                cC0 = MFMA32(Afh[0][j][kc], Gl[j][kc], cC0);
                cC1 = MFMA32(Afh[1][j][kc], Gl[j][kc], cC1);
                cD0 = MFMA32(Afl[0][j][kc], Gh[j][kc], cD0);
                cD1 = MFMA32(Afl[1][j][kc], Gh[j][kc], cD1);
            }
        ac0 = (cA0 + cB0) + (cC0 + cD0);
        ac1 = (cA1 + cB1) + (cC1 + cD1);
        // feedback: new G frags via permlane swaps (no LDS)
        feedback(ac0, Gh[0][0], Gl[0][0], Gh[0][1], Gl[0][1]);
        feedback(ac1, Gh[1][0], Gl[1][0], Gh[1][1], Gl[1][1]);
        if (DOY) {
            float* yp = yb + (long)(t0 + st) * 64;
#pragma unroll
            for (int i = 0; i < 2; ++i) {
                // 3 independent chains of 4 (C.Gh | C.Gl | D.x)
                f32x16 yA = z16(), yB = z16(), yC = z16();
#pragma unroll
                for (int jr = 0; jr < 2; ++jr)
#pragma unroll
                    for (int kc = 0; kc < 2; ++kc) {
                        yA = MFMA32(Cf[i][jr][kc], Gh[jr][kc], yA);
                        yB = MFMA32(Cf[i][jr][kc], Gl[jr][kc], yB);
                        yC = MFMA32(Df[i][jr][kc], XB[jr][kc], yC);
                    }
                f32x16 ya = (yA + yB) + yC;
#pragma unroll
                for (int m = 0; m < 4; ++m) {
                    f32x4 v;
                    v[0] = ya[4 * m]; v[1] = ya[4 * m + 1];
                    v[2] = ya[4 * m + 2]; v[3] = ya[4 * m + 3];
                    *(f32x4*)(yp + 32 * i + 8 * m + 4 * hl) = v;
                }
            }
        }
        if (!DOY && st == LCH - 1) {
            float* fp = fbuf + ((long)c * 128 + brow) * 64;
#pragma unroll
            for (int m = 0; m < 4; ++m) {
                f32x4 v0, v1;
                v0[0] = ac0[4 * m]; v0[1] = ac0[4 * m + 1];
                v0[2] = ac0[4 * m + 2]; v0[3] = ac0[4 * m + 3];
                v1[0] = ac1[4 * m]; v1[1] = ac1[4 * m + 1];
                v1[2] = ac1[4 * m + 2]; v1[3] = ac1[4 * m + 3];
                *(f32x4*)(fp + 8 * m + 4 * hl) = v0;
                *(f32x4*)(fp + 32 + 8 * m + 4 * hl) = v1;
            }
        }
        // rotate x: XB <- XF(t+1); prefetch XF(t+2) (clamped)
        CVTX();
        int nt = st + 2;
        if (t0 + nt > T_SEQ - 1) nt = T_SEQ - 1 - t0;
        LOADX(nt);
    }
#undef LOADX
#undef CVTX
}

__global__ __launch_bounds__(64, 1) void k_scan1(const float* __restrict__ x,
        const __bf16* __restrict__ A_hi, const __bf16* __restrict__ A_lo,
        const __bf16* __restrict__ B_bf, float* __restrict__ fbuf) {
    scan_core<false>(x, nullptr, A_hi, A_lo, B_bf, nullptr, nullptr, fbuf, nullptr);
}

__global__ __launch_bounds__(64, 1) void k_scan2(const float* __restrict__ x,
        const float* __restrict__ Sbuf,
        const __bf16* __restrict__ A_hi, const __bf16* __restrict__ A_lo,
        const __bf16* __restrict__ B_bf, const __bf16* __restrict__ C_bf,
        const __bf16* __restrict__ D_bf, float* __restrict__ y) {
    scan_core<true>(x, Sbuf, A_hi, A_lo, B_bf, C_bf, D_bf, nullptr, y);
}

// ---------------- boundary scans (round-18 proven) -------------------------
__global__ __launch_bounds__(256) void k_bound1(const float* __restrict__ P,
        const float* __restrict__ fbuf, float* __restrict__ Fsup, int nper) {
    int wid = blockIdx.x * 4 + (threadIdx.x >> 6);
    int lane = threadIdx.x & 63;
    int s = wid >> 7, batch = wid & 127;
    float Pr[64];
    const f32x4* P4 = (const f32x4*)(P + lane * 64);
#pragma unroll
    for (int qq = 0; qq < 16; ++qq) {
        f32x4 v = P4[qq];
        Pr[qq*4] = v[0]; Pr[qq*4+1] = v[1]; Pr[qq*4+2] = v[2]; Pr[qq*4+3] = v[3];
    }
    float S = 0.f;
    for (int i = 0; i < nper; ++i) {
        int c = s * nper + i;
        float fv = fbuf[((long)c * 128 + batch) * 64 + lane];
        float a0 = fv, a1 = 0.f;
#pragma unroll
        for (int m = 0; m < 64; m += 2) {
            a0 = fmaf(Pr[m],     bcast(S, m),     a0);
            a1 = fmaf(Pr[m + 1], bcast(S, m + 1), a1);
        }
        S = a0 + a1;
    }
    Fsup[((long)s * 128 + batch) * 64 + lane] = S;
}

__global__ __launch_bounds__(256) void k_bsuper(const float* __restrict__ P,
        float* __restrict__ Fsup, int nsup) {
    int batch = blockIdx.x * 4 + (threadIdx.x >> 6);
    int lane = threadIdx.x & 63;
    float Pr[64];
    const f32x4* P4 = (const f32x4*)(P + lane * 64);
#pragma unroll
    for (int qq = 0; qq < 16; ++qq) {
        f32x4 v = P4[qq];
        Pr[qq*4] = v[0]; Pr[qq*4+1] = v[1]; Pr[qq*4+2] = v[2]; Pr[qq*4+3] = v[3];
    }
    float E = 0.f;
    for (int s = 0; s < nsup; ++s) {
        long idx = ((long)s * 128 + batch) * 64 + lane;
        float tmp = Fsup[idx];
        Fsup[idx] = E;
        float a0 = tmp, a1 = 0.f;
#pragma unroll
        for (int m = 0; m < 64; m += 2) {
            a0 = fmaf(Pr[m],     bcast(E, m),     a0);
            a1 = fmaf(Pr[m + 1], bcast(E, m + 1), a1);
        }
        E = a0 + a1;
    }
}

__global__ __launch_bounds__(256) void k_bound2(const float* __restrict__ P,
        const float* __restrict__ Fsup, float* __restrict__ fbuf, int nper) {
    int wid = blockIdx.x * 4 + (threadIdx.x >> 6);
    int lane = threadIdx.x & 63;
    int s = wid >> 7, batch = wid & 127;
    float Pr[64];
    const f32x4* P4 = (const f32x4*)(P + lane * 64);
#pragma unroll
    for (int qq = 0; qq < 16; ++qq) {
        f32x4 v = P4[qq];
        Pr[qq*4] = v[0]; Pr[qq*4+1] = v[1]; Pr[qq*4+2] = v[2]; Pr[qq*4+3] = v[3];
    }
    float S = Fsup[((long)s * 128 + batch) * 64 + lane];
    for (int i = 0; i < nper; ++i) {
        int c = s * nper + i;
        long idx = ((long)c * 128 + batch) * 64 + lane;
        float tmp = fbuf[idx];
        fbuf[idx] = S;                 // entry state of chunk c
        float a0 = tmp, a1 = 0.f;
#pragma unroll
        for (int m = 0; m < 64; m += 2) {
            a0 = fmaf(Pr[m],     bcast(S, m),     a0);
            a1 = fmaf(Pr[m + 1], bcast(S, m + 1), a1);
        }
        S = a0 + a1;
    }
}

extern "C" void kernel_launch(void* const* d_in, const int* in_sizes, int n_in,
                              void* d_out, int out_size, void* d_ws, size_t ws_size,
                              hipStream_t stream) {
    const float* x = (const float*)d_in[0];
    const float* A = (const float*)d_in[1];
    const float* B = (const float*)d_in[2];
    const float* C = (const float*)d_in[3];
    const float* D = (const float*)d_in[4];
    float* y = (float*)d_out;
    char* ws = (char*)d_ws;

    float*  fbuf = (float*)(ws);                  // 256*128*64*4 = 8,388,608
    float*  Fsup = (float*)(ws + 8388608);        // 16*128*64*4 = 524,288
    float*  P8   = (float*)(ws + 8912896);        // 16,384
    float*  P128 = (float*)(ws + 8929280);        // 16,384
    __bf16* A_hi = (__bf16*)(ws + 8945664);       // 8,192 each
    __bf16* A_lo = (__bf16*)(ws + 8953856);
    __bf16* B_bf = (__bf16*)(ws + 8962048);
    __bf16* C_bf = (__bf16*)(ws + 8970240);
    __bf16* D_bf = (__bf16*)(ws + 8978432);
    // total 8,986,624 B

    k_prep<<<2, 256, 0, stream>>>(A, B, C, D, P8, P128,
                                  A_hi, A_lo, B_bf, C_bf, D_bf);
    k_scan1<<<1024, 64, 0, stream>>>(x, A_hi, A_lo, B_bf, fbuf);
    k_bound1<<<512, 256, 0, stream>>>(P8, fbuf, Fsup, 16);
    k_bsuper<<<32, 256, 0, stream>>>(P128, Fsup, 16);
    k_bound2<<<512, 256, 0, stream>>>(P8, Fsup, fbuf, 16);
    k_scan2<<<1024, 64, 0, stream>>>(x, fbuf, A_hi, A_lo, B_bf, C_bf, D_bf, y);
}

// Round 22
// 91.953 us; speedup vs baseline: 1.0932x; 1.0666x over previous
//
#include <hip/hip_runtime.h>

// SSM: h_t = A h_{t-1} + B x_t ; y_t = C h_t + D x_t
// BATCH=128, T=2048, N=64, f32. A symmetric -> transposed state:
//   G = h^T (64 x 32batch): G_t = A*G_{t-1} + B*x_t^T
// 32x32x16 MFMA tiles, 32 batches/wave, NO LDS in scans; state feedback
// (C/D layout -> B-operand frags) via __builtin_amdgcn_permlane32_swap.
// A split hi/lo (3-mult); B,C,D,x plain bf16.
// Round 22 = round 9 VERBATIM (measured champion: 91.9 us, absmax 0.5).
// Rounds 16-21 proved all perturbations (chain len, wave count, load
// coalescing, ILP chains, staging vectorization) neutral-to-worse.

#define T_SEQ 2048
#define LCH 16
#define NCH 128
#define NSUP 8

typedef __bf16 bf16x8 __attribute__((ext_vector_type(8)));
typedef float f32x4 __attribute__((ext_vector_type(4)));
typedef float f32x16 __attribute__((ext_vector_type(16)));
typedef unsigned int u32;
typedef unsigned int u32x2 __attribute__((ext_vector_type(2)));

#define MFMA32(a, b, c) __builtin_amdgcn_mfma_f32_32x32x16_bf16(a, b, c, 0, 0, 0)
#define MFMA16(a, b, c) __builtin_amdgcn_mfma_f32_16x16x32_bf16(a, b, c, 0, 0, 0)

__device__ __forceinline__ float bcast(float v, int l) {
    return __int_as_float(__builtin_amdgcn_readlane(__float_as_int(v), l));
}
__device__ __forceinline__ u32 pk2f(float a, float b) {
    union { __bf16 h[2]; u32 u; } z;
    z.h[0] = (__bf16)a; z.h[1] = (__bf16)b; return z.u;
}
__device__ __forceinline__ u32 pk2h(__bf16 a, __bf16 b) {
    union { __bf16 h[2]; u32 u; } z;
    z.h[0] = a; z.h[1] = b; return z.u;
}
__device__ __forceinline__ bf16x8 mk8(u32 a, u32 b, u32 c, u32 d) {
    union { u32 u[4]; bf16x8 v; } z;
    z.u[0] = a; z.u[1] = b; z.u[2] = c; z.u[3] = d; return z.v;
}
// swap upper 32 lanes of a with lower 32 lanes of b (both updated).
// Builtin (NOT raw asm): compiler handles gfx950 VALU<->permlane hazards.
__device__ __forceinline__ void plswap(u32& a, u32& b) {
    u32x2 r = __builtin_amdgcn_permlane32_swap(a, b, false, false);
    a = r[0]; b = r[1];
}
__device__ __forceinline__ f32x16 z16() {
    f32x16 z;
#pragma unroll
    for (int e = 0; e < 16; ++e) z[e] = 0.f;
    return z;
}
__device__ __forceinline__ void split8(f32x4 a, f32x4 b, bf16x8& hi, bf16x8& lo) {
#pragma unroll
    for (int i = 0; i < 4; ++i) {
        float v = a[i]; __bf16 h = (__bf16)v; hi[i] = h; lo[i] = (__bf16)(v - (float)h);
        v = b[i]; h = (__bf16)v; hi[4 + i] = h; lo[4 + i] = (__bf16)(v - (float)h);
    }
}

// C/D tile (f32x16) -> B-operand frags (kc=0,1) hi+lo, via permlane swaps.
// C/D: reg r -> row (r&3)+8*(r>>2)+4*hl.  B-frag kc: elem e -> row 16kc+8hl+e.
__device__ __forceinline__ void feedback(const f32x16& ac,
        bf16x8& gh0, bf16x8& gl0, bf16x8& gh1, bf16x8& gl1) {
    __bf16 hb[16]; float lo[16];
#pragma unroll
    for (int e = 0; e < 16; ++e) { hb[e] = (__bf16)ac[e]; lo[e] = ac[e] - (float)hb[e]; }
    u32 a0 = pk2h(hb[0], hb[1]),  a1 = pk2h(hb[2], hb[3]);
    u32 b0 = pk2h(hb[4], hb[5]),  b1 = pk2h(hb[6], hb[7]);
    u32 c0 = pk2h(hb[8], hb[9]),  c1 = pk2h(hb[10], hb[11]);
    u32 d0 = pk2h(hb[12], hb[13]), d1 = pk2h(hb[14], hb[15]);
    plswap(a0, b0); plswap(a1, b1);
    gh0 = mk8(a0, a1, b0, b1);
    plswap(c0, d0); plswap(c1, d1);
    gh1 = mk8(c0, c1, d0, d1);
    u32 e0 = pk2f(lo[0], lo[1]),  e1 = pk2f(lo[2], lo[3]);
    u32 f0 = pk2f(lo[4], lo[5]),  f1 = pk2f(lo[6], lo[7]);
    u32 g0 = pk2f(lo[8], lo[9]),  g1 = pk2f(lo[10], lo[11]);
    u32 h0 = pk2f(lo[12], lo[13]), h1 = pk2f(lo[14], lo[15]);
    plswap(e0, f0); plswap(e1, f1);
    gl0 = mk8(e0, e1, f0, f1);
    plswap(g0, h0); plswap(g1, h1);
    gl1 = mk8(g0, g1, h0, h1);
}

// ---------------- k_prep (16x16 split-MFMA squarings; round-6 proven) ------
__device__ __forceinline__ void mmstep(int w, int fr, int fq,
        const __bf16 (*Xh)[72], const __bf16 (*Xl)[72],
        const __bf16 (*Yh)[72], const __bf16 (*Yl)[72],
        __bf16 (*Dh)[72], __bf16 (*Dl)[72]) {
    f32x4 accs[4];
#pragma unroll
    for (int mt = 0; mt < 4; ++mt) {
        f32x4 acc = {0.f, 0.f, 0.f, 0.f};
#pragma unroll
        for (int kk = 0; kk < 2; ++kk) {
            bf16x8 xh = *(const bf16x8*)&Xh[mt * 16 + fr][fq * 8 + kk * 32];
            bf16x8 xl = *(const bf16x8*)&Xl[mt * 16 + fr][fq * 8 + kk * 32];
            bf16x8 yh = *(const bf16x8*)&Yh[w * 16 + fr][fq * 8 + kk * 32];
            bf16x8 yl = *(const bf16x8*)&Yl[w * 16 + fr][fq * 8 + kk * 32];
            acc = MFMA16(xh, yh, acc);
            acc = MFMA16(xh, yl, acc);
            acc = MFMA16(xl, yh, acc);
        }
        accs[mt] = acc;
    }
    __syncthreads();
#pragma unroll
    for (int mt = 0; mt < 4; ++mt)
#pragma unroll
        for (int r = 0; r < 4; ++r) {
            float v = accs[mt][r]; __bf16 h = (__bf16)v;
            Dh[mt * 16 + fq * 4 + r][w * 16 + fr] = h;
            Dl[mt * 16 + fq * 4 + r][w * 16 + fr] = (__bf16)(v - (float)h);
        }
    __syncthreads();
}

__global__ __launch_bounds__(256) void k_prep(const float* __restrict__ A,
        const float* __restrict__ B, const float* __restrict__ C,
        const float* __restrict__ D, float* __restrict__ P16f,
        float* __restrict__ P256f,
        __bf16* __restrict__ A_hi, __bf16* __restrict__ A_lo,
        __bf16* __restrict__ B_bf, __bf16* __restrict__ C_bf,
        __bf16* __restrict__ D_bf) {
    if (blockIdx.x == 1) {
        for (int i = threadIdx.x; i < 4096; i += 256) {
            float a = A[i]; __bf16 h = (__bf16)a;
            A_hi[i] = h; A_lo[i] = (__bf16)(a - (float)h);
            B_bf[i] = (__bf16)B[i];
            C_bf[i] = (__bf16)C[i];
            D_bf[i] = (__bf16)D[i];
        }
        return;
    }
    __shared__ __align__(16) __bf16 X1h[64][72], X1l[64][72];
    __shared__ __align__(16) __bf16 X2h[64][72], X2l[64][72];
    int w = threadIdx.x >> 6, lane = threadIdx.x & 63;
    int fr = lane & 15, fq = lane >> 4;
    for (int i = threadIdx.x; i < 4096; i += 256) {
        int r = i >> 6, cc = i & 63;
        float a = A[i]; __bf16 h = (__bf16)a;
        X1h[r][cc] = h; X1l[r][cc] = (__bf16)(a - (float)h);
    }
    __syncthreads();
    __bf16 (*curh)[72] = X1h, (*curl)[72] = X1l;
    __bf16 (*oth)[72] = X2h, (*otl)[72] = X2l;
    for (int sq = 0; sq < 8; ++sq) {   // A^2 .. A^256
        mmstep(w, fr, fq, curh, curl, curh, curl, oth, otl);
        { __bf16 (*t1)[72] = curh; curh = oth; oth = t1;
          __bf16 (*t2)[72] = curl; curl = otl; otl = t2; }
        if (sq == 3) {                 // A^16
            for (int i = threadIdx.x; i < 4096; i += 256)
                P16f[i] = (float)curh[i >> 6][i & 63] + (float)curl[i >> 6][i & 63];
        }
    }
    for (int i = threadIdx.x; i < 4096; i += 256)
        P256f[i] = (float)curh[i >> 6][i & 63] + (float)curl[i >> 6][i & 63];
}

// ---------------- scan core (32x32 tiles, LDS-free) ------------------------
// Layouts (mfma_f32_32x32x16_bf16):
//   A-op: lane l -> M[row=l&31][k=8*(l>>5)+e (+16kc)]
//   B-op: lane l -> M[k=8*(l>>5)+e (+16kc)][col=l&31]
//   C/D : lane l -> D[row=(r&3)+8*(r>>2)+4*(l>>5)][col=l&31]
template<bool DOY>
__device__ __forceinline__ void scan_core(const float* __restrict__ x,
        const float* __restrict__ Sbuf,
        const __bf16* __restrict__ A_hi, const __bf16* __restrict__ A_lo,
        const __bf16* __restrict__ B_bf, const __bf16* __restrict__ C_bf,
        const __bf16* __restrict__ D_bf,
        float* __restrict__ fbuf, float* __restrict__ y) {
    int lane = threadIdx.x & 63;
    int bcol = lane & 31;
    int hl = lane >> 5;
    int wid = blockIdx.x;
    int g = wid >> 7;            // batch group 0..3
    int c = wid & 127;           // chunk
    int t0 = c * LCH;
    long brow = (long)(g * 32 + bcol);

    bf16x8 Afh[2][2][2], Afl[2][2][2], Bf[2][2][2], Cf[2][2][2], Df[2][2][2];
#pragma unroll
    for (int i = 0; i < 2; ++i)
#pragma unroll
        for (int j = 0; j < 2; ++j)
#pragma unroll
            for (int kc = 0; kc < 2; ++kc) {
                int off = (32 * i + bcol) * 64 + 32 * j + 16 * kc + 8 * hl;
                Afh[i][j][kc] = *(const bf16x8*)(A_hi + off);
                Afl[i][j][kc] = *(const bf16x8*)(A_lo + off);
                Bf[i][j][kc]  = *(const bf16x8*)(B_bf + off);
                if (DOY) {
                    Cf[i][j][kc] = *(const bf16x8*)(C_bf + off);
                    Df[i][j][kc] = *(const bf16x8*)(D_bf + off);
                }
            }

    bf16x8 Gh[2][2], Gl[2][2];
    if (DOY) {
        const float* Sp = Sbuf + ((long)c * 128 + brow) * 64;
#pragma unroll
        for (int jr = 0; jr < 2; ++jr)
#pragma unroll
            for (int kc = 0; kc < 2; ++kc) {
                int n0 = 32 * jr + 16 * kc + 8 * hl;
                f32x4 s0 = *(const f32x4*)(Sp + n0);
                f32x4 s1 = *(const f32x4*)(Sp + n0 + 4);
                split8(s0, s1, Gh[jr][kc], Gl[jr][kc]);
            }
    } else {
#pragma unroll
        for (int jr = 0; jr < 2; ++jr)
#pragma unroll
            for (int kc = 0; kc < 2; ++kc) {
                Gh[jr][kc] = (bf16x8)(__bf16)0.f;
                Gl[jr][kc] = (bf16x8)(__bf16)0.f;
            }
    }

    const float* xb = x + (brow * T_SEQ + t0) * 64 + 8 * hl;
    f32x4 XF[8]; bf16x8 XB[2][2];
#define LOADX(dt) { const float* p = xb + (long)(dt) * 64;                     \
    XF[0] = *(const f32x4*)(p);      XF[1] = *(const f32x4*)(p + 4);           \
    XF[2] = *(const f32x4*)(p + 16); XF[3] = *(const f32x4*)(p + 20);          \
    XF[4] = *(const f32x4*)(p + 32); XF[5] = *(const f32x4*)(p + 36);          \
    XF[6] = *(const f32x4*)(p + 48); XF[7] = *(const f32x4*)(p + 52); }
#define CVTX() {                                                               \
    XB[0][0] = mk8(pk2f(XF[0][0], XF[0][1]), pk2f(XF[0][2], XF[0][3]),         \
                   pk2f(XF[1][0], XF[1][1]), pk2f(XF[1][2], XF[1][3]));        \
    XB[0][1] = mk8(pk2f(XF[2][0], XF[2][1]), pk2f(XF[2][2], XF[2][3]),         \
                   pk2f(XF[3][0], XF[3][1]), pk2f(XF[3][2], XF[3][3]));        \
    XB[1][0] = mk8(pk2f(XF[4][0], XF[4][1]), pk2f(XF[4][2], XF[4][3]),         \
                   pk2f(XF[5][0], XF[5][1]), pk2f(XF[5][2], XF[5][3]));        \
    XB[1][1] = mk8(pk2f(XF[6][0], XF[6][1]), pk2f(XF[6][2], XF[6][3]),         \
                   pk2f(XF[7][0], XF[7][1]), pk2f(XF[7][2], XF[7][3])); }

    LOADX(0); CVTX(); LOADX(1);

    float* yb = DOY ? (y + brow * T_SEQ * 64) : nullptr;
    f32x16 ac0, ac1;
#pragma unroll
    for (int st = 0; st < LCH; ++st) {
        // u = B * x^T into fresh accumulators
        ac0 = z16(); ac1 = z16();
#pragma unroll
        for (int j = 0; j < 2; ++j)
#pragma unroll
            for (int kc = 0; kc < 2; ++kc) {
                ac0 = MFMA32(Bf[0][j][kc], XB[j][kc], ac0);
                ac1 = MFMA32(Bf[1][j][kc], XB[j][kc], ac1);
            }
        // + A * G  (3-mult split)
#pragma unroll
        for (int jr = 0; jr < 2; ++jr)
#pragma unroll
            for (int kc = 0; kc < 2; ++kc) {
                ac0 = MFMA32(Afh[0][jr][kc], Gh[jr][kc], ac0);
                ac0 = MFMA32(Afh[0][jr][kc], Gl[jr][kc], ac0);
                ac0 = MFMA32(Afl[0][jr][kc], Gh[jr][kc], ac0);
                ac1 = MFMA32(Afh[1][jr][kc], Gh[jr][kc], ac1);
                ac1 = MFMA32(Afh[1][jr][kc], Gl[jr][kc], ac1);
                ac1 = MFMA32(Afl[1][jr][kc], Gh[jr][kc], ac1);
            }
        // feedback: new G frags via permlane swaps (no LDS)
        feedback(ac0, Gh[0][0], Gl[0][0], Gh[0][1], Gl[0][1]);
        feedback(ac1, Gh[1][0], Gl[1][0], Gh[1][1], Gl[1][1]);
        if (DOY) {
            float* yp = yb + (long)(t0 + st) * 64;
#pragma unroll
            for (int i = 0; i < 2; ++i) {
                f32x16 ya = z16();
#pragma unroll
                for (int jr = 0; jr < 2; ++jr)
#pragma unroll
                    for (int kc = 0; kc < 2; ++kc) {
                        ya = MFMA32(Cf[i][jr][kc], Gh[jr][kc], ya);
                        ya = MFMA32(Cf[i][jr][kc], Gl[jr][kc], ya);
                        ya = MFMA32(Df[i][jr][kc], XB[jr][kc], ya);
                    }
#pragma unroll
                for (int m = 0; m < 4; ++m) {
                    f32x4 v;
                    v[0] = ya[4 * m]; v[1] = ya[4 * m + 1];
                    v[2] = ya[4 * m + 2]; v[3] = ya[4 * m + 3];
                    *(f32x4*)(yp + 32 * i + 8 * m + 4 * hl) = v;
                }
            }
        }
        if (!DOY && st == LCH - 1) {
            float* fp = fbuf + ((long)c * 128 + brow) * 64;
#pragma unroll
            for (int m = 0; m < 4; ++m) {
                f32x4 v0, v1;
                v0[0] = ac0[4 * m]; v0[1] = ac0[4 * m + 1];
                v0[2] = ac0[4 * m + 2]; v0[3] = ac0[4 * m + 3];
                v1[0] = ac1[4 * m]; v1[1] = ac1[4 * m + 1];
                v1[2] = ac1[4 * m + 2]; v1[3] = ac1[4 * m + 3];
                *(f32x4*)(fp + 8 * m + 4 * hl) = v0;
                *(f32x4*)(fp + 32 + 8 * m + 4 * hl) = v1;
            }
        }
        // rotate x: XB <- XF(t+1); prefetch XF(t+2) (clamped)
        CVTX();
        int nt = st + 2;
        if (t0 + nt > T_SEQ - 1) nt = T_SEQ - 1 - t0;
        LOADX(nt);
    }
#undef LOADX
#undef CVTX
}

__global__ __launch_bounds__(64, 1) void k_scan1(const float* __restrict__ x,
        const __bf16* __restrict__ A_hi, const __bf16* __restrict__ A_lo,
        const __bf16* __restrict__ B_bf, float* __restrict__ fbuf) {
    scan_core<false>(x, nullptr, A_hi, A_lo, B_bf, nullptr, nullptr, fbuf, nullptr);
}

__global__ __launch_bounds__(64, 1) void k_scan2(const float* __restrict__ x,
        const float* __restrict__ Sbuf,
        const __bf16* __restrict__ A_hi, const __bf16* __restrict__ A_lo,
        const __bf16* __restrict__ B_bf, const __bf16* __restrict__ C_bf,
        const __bf16* __restrict__ D_bf, float* __restrict__ y) {
    scan_core<true>(x, Sbuf, A_hi, A_lo, B_bf, C_bf, D_bf, nullptr, y);
}

// ---------------- boundary scans (2-level, f32 readlane) -------------------
__global__ __launch_bounds__(256) void k_bound1(const float* __restrict__ P16f,
        const float* __restrict__ fbuf, float* __restrict__ Fsup) {
    int wid = blockIdx.x * 4 + (threadIdx.x >> 6);
    int lane = threadIdx.x & 63;
    int s = wid >> 7, batch = wid & 127;
    float Pr[64];
    const f32x4* P4 = (const f32x4*)(P16f + lane * 64);
#pragma unroll
    for (int qq = 0; qq < 16; ++qq) {
        f32x4 v = P4[qq];
        Pr[qq*4] = v[0]; Pr[qq*4+1] = v[1]; Pr[qq*4+2] = v[2]; Pr[qq*4+3] = v[3];
    }
    float S = 0.f;
    for (int i = 0; i < 16; ++i) {
        int c = s * 16 + i;
        float fv = fbuf[((long)c * 128 + batch) * 64 + lane];
        float a0 = fv, a1 = 0.f;
#pragma unroll
        for (int m = 0; m < 64; m += 2) {
            a0 = fmaf(Pr[m],     bcast(S, m),     a0);
            a1 = fmaf(Pr[m + 1], bcast(S, m + 1), a1);
        }
        S = a0 + a1;
    }
    Fsup[((long)s * 128 + batch) * 64 + lane] = S;
}

__global__ __launch_bounds__(256) void k_bsuper(const float* __restrict__ P256f,
        float* __restrict__ Fsup) {
    int batch = blockIdx.x * 4 + (threadIdx.x >> 6);
    int lane = threadIdx.x & 63;
    float Pr[64];
    const f32x4* P4 = (const f32x4*)(P256f + lane * 64);
#pragma unroll
    for (int qq = 0; qq < 16; ++qq) {
        f32x4 v = P4[qq];
        Pr[qq*4] = v[0]; Pr[qq*4+1] = v[1]; Pr[qq*4+2] = v[2]; Pr[qq*4+3] = v[3];
    }
    float E = 0.f;
    for (int s = 0; s < NSUP; ++s) {
        long idx = ((long)s * 128 + batch) * 64 + lane;
        float tmp = Fsup[idx];
        Fsup[idx] = E;
        float a0 = tmp, a1 = 0.f;
#pragma unroll
        for (int m = 0; m < 64; m += 2) {
            a0 = fmaf(Pr[m],     bcast(E, m),     a0);
            a1 = fmaf(Pr[m + 1], bcast(E, m + 1), a1);
        }
        E = a0 + a1;
    }
}

__global__ __launch_bounds__(256) void k_bound2(const float* __restrict__ P16f,
        const float* __restrict__ Fsup, float* __restrict__ fbuf) {
    int wid = blockIdx.x * 4 + (threadIdx.x >> 6);
    int lane = threadIdx.x & 63;
    int s = wid >> 7, batch = wid & 127;
    float Pr[64];
    const f32x4* P4 = (const f32x4*)(P16f + lane * 64);
#pragma unroll
    for (int qq = 0; qq < 16; ++qq) {
        f32x4 v = P4[qq];
        Pr[qq*4] = v[0]; Pr[qq*4+1] = v[1]; Pr[qq*4+2] = v[2]; Pr[qq*4+3] = v[3];
    }
    float S = Fsup[((long)s * 128 + batch) * 64 + lane];
    for (int i = 0; i < 16; ++i) {
        int c = s * 16 + i;
        long idx = ((long)c * 128 + batch) * 64 + lane;
        float tmp = fbuf[idx];
        fbuf[idx] = S;                 // entry state of chunk c
        float a0 = tmp, a1 = 0.f;
#pragma unroll
        for (int m = 0; m < 64; m += 2) {
            a0 = fmaf(Pr[m],     bcast(S, m),     a0);
            a1 = fmaf(Pr[m + 1], bcast(S, m + 1), a1);
        }
        S = a0 + a1;
    }
}

extern "C" void kernel_launch(void* const* d_in, const int* in_sizes, int n_in,
                              void* d_out, int out_size, void* d_ws, size_t ws_size,
                              hipStream_t stream) {
    const float* x = (const float*)d_in[0];
    const float* A = (const float*)d_in[1];
    const float* B = (const float*)d_in[2];
    const float* C = (const float*)d_in[3];
    const float* D = (const float*)d_in[4];
    float* y = (float*)d_out;
    char* ws = (char*)d_ws;

    float*  fbuf = (float*)(ws);                  // 128*128*64*4 = 4 MB
    float*  Fsup = (float*)(ws + 4194304);        // 8*128*64*4 = 256 KB
    float*  P16f = (float*)(ws + 4456448);        // 16 KB
    float*  P256f= (float*)(ws + 4472832);        // 16 KB
    __bf16* A_hi = (__bf16*)(ws + 4489216);       // 8 KB each
    __bf16* A_lo = (__bf16*)(ws + 4497408);
    __bf16* B_bf = (__bf16*)(ws + 4505600);
    __bf16* C_bf = (__bf16*)(ws + 4513792);
    __bf16* D_bf = (__bf16*)(ws + 4521984);
    // total: 4,530,176 bytes (round-6-proven footprint)

    k_prep<<<2, 256, 0, stream>>>(A, B, C, D, P16f, P256f,
                                  A_hi, A_lo, B_bf, C_bf, D_bf);
    k_scan1<<<512, 64, 0, stream>>>(x, A_hi, A_lo, B_bf, fbuf);
    k_bound1<<<256, 256, 0, stream>>>(P16f, fbuf, Fsup);
    k_bsuper<<<32, 256, 0, stream>>>(P256f, Fsup);
    k_bound2<<<256, 256, 0, stream>>>(P16f, Fsup, fbuf);
    k_scan2<<<512, 64, 0, stream>>>(x, fbuf, A_hi, A_lo, B_bf, C_bf, D_bf, y);
}